// Round 5
// baseline (270.683 us; speedup 1.0000x reference)
//
#include <hip/hip_runtime.h>
#include <math.h>

// Problem constants (from reference setup_inputs)
constexpr int B = 8, C = 64, W = 240, H = 240, N = 2000, M = 8;
constexpr int WH = W * H;               // 57600
constexpr float MARGIN = 0.5f;
constexpr float EPS = 1e-7f;

__device__ __forceinline__ float wave_sum64(float v) {
#pragma unroll
    for (int s = 32; s > 0; s >>= 1) v += __shfl_xor(v, s, 64);
    return v;  // all 64 lanes hold the full sum
}

// ---------------------------------------------------------------------------
// Kernel 1: transpose out2 (b, c, wh) -> (b, wh, c).
// float4 on both global sides (1KB/wave-instr), XOR-swizzled 64KB LDS tile.
// Tile: 64 channels x 256 positions.  WH/256 = 225 exactly.
// ---------------------------------------------------------------------------
constexpr int TP = 256;                        // positions per tile
constexpr int TBLOCKS = B * (WH / TP);         // 8 * 225 = 1800

__global__ __launch_bounds__(256) void transpose_out2(
    const float* __restrict__ src, float* __restrict__ dst)
{
    __shared__ float tile[C * TP];             // 64KB; logical [c][pos], swizzled
    const int b    = blockIdx.x / (WH / TP);
    const int p0   = (blockIdx.x % (WH / TP)) * TP;
    const int lane = threadIdx.x & 63;
    const int wave = threadIdx.x >> 6;

    // READ phase: wave w handles channels [w*16, w*16+16).
    // One float4 load per channel covers all 256 positions across 64 lanes.
    const float4* s4base = (const float4*)(src + ((size_t)b * C) * WH + p0);
    float4* t4 = (float4*)tile;
#pragma unroll
    for (int i = 0; i < 16; ++i) {
        const int c = wave * 16 + i;
        const float4 v = s4base[(size_t)c * (WH / 4) + lane];
        // swizzled float4 slot within row c
        t4[c * (TP / 4) + (lane ^ ((c >> 2) & 7))] = v;
    }
    __syncthreads();

    // WRITE phase: wave w handles positions [w*64, w*64+64), 4 per iter.
    // lane&15 -> channel quad, lane>>4 -> position within quad of positions.
    float4* d4 = (float4*)dst;
#pragma unroll
    for (int i = 0; i < 16; ++i) {
        const int p  = wave * 64 + i * 4 + (lane >> 4);   // position in tile
        const int c0 = (lane & 15) * 4;
        float4 o;
        {
            const int c = c0 + 0;
            o.x = tile[c * TP + (p ^ (((c >> 2) & 7) << 2))];
        }
        {
            const int c = c0 + 1;
            o.y = tile[c * TP + (p ^ (((c >> 2) & 7) << 2))];
        }
        {
            const int c = c0 + 2;
            o.z = tile[c * TP + (p ^ (((c >> 2) & 7) << 2))];
        }
        {
            const int c = c0 + 3;
            o.w = tile[c * TP + (p ^ (((c >> 2) & 7) << 2))];
        }
        d4[((size_t)b * WH + p0 + p) * (C / 4) + (lane & 15)] = o;
    }
}

// ---------------------------------------------------------------------------
// Kernel 2: gather + triplet math.  1 point per wave, 16000 waves. (unchanged)
// ---------------------------------------------------------------------------
constexpr int GW = 4;                          // waves per block
constexpr int GBLOCKS = (B * N) / GW;          // 4000

__global__ __launch_bounds__(256) void triplet_gather(
    const float* __restrict__ out1, const float* __restrict__ out2T,
    const int2* __restrict__ xy1, const int2* __restrict__ xy2,
    const int2* __restrict__ nm2, float* __restrict__ partial)
{
    const int lane = threadIdx.x & 63;         // = channel
    const int wave = threadIdx.x >> 6;
    const int p = blockIdx.x * GW + wave;      // 0..15999
    const int b = p / N, n = p - b * N;

    // f1: direct strided gather from out1 (not transposed)
    const int2 q1 = xy1[(size_t)b * N + n];
    const float f1 = out1[(size_t)(b * C + lane) * WH + q1.x * H + q1.y];

    const float* base2 = out2T + (size_t)b * WH * C;

    // f2: contiguous 256B vector from transposed out2
    const int2 q2 = xy2[(size_t)b * N + n];
    const float f2 = base2[(size_t)(q2.x * H + q2.y) * C + lane];
    const float dp = f1 - f2;
    const float pos_dist = sqrtf(wave_sum64(dp * dp) + EPS);

    float neg_sum = 0.0f;
#pragma unroll
    for (int j = 0; j < M; ++j) {
        const int2 qn = nm2[(((size_t)b * M + j) * N) + n];
        const float fn = base2[(size_t)(qn.x * H + qn.y) * C + lane];
        const float dn = f1 - fn;
        neg_sum += sqrtf(wave_sum64(dn * dn) + EPS);
    }

    const float v = pos_dist - neg_sum * (1.0f / M) + MARGIN;
    const float res = (v > 0.0f) ? v : 0.0f;

    __shared__ float sm[GW];
    if (lane == 0) sm[wave] = res;
    __syncthreads();
    if (threadIdx.x == 0) {
        float s = 0.0f;
#pragma unroll
        for (int i = 0; i < GW; ++i) s += sm[i];
        partial[blockIdx.x] = s;
    }
}

// ---------------------------------------------------------------------------
// Fallback direct kernel (used only if ws too small for the transpose buffer)
// ---------------------------------------------------------------------------
constexpr int FBLOCKS = 2000, FW = 4;

__global__ __launch_bounds__(256) void triplet_direct(
    const float* __restrict__ out1, const float* __restrict__ out2,
    const int2* __restrict__ xy1, const int2* __restrict__ xy2,
    const int2* __restrict__ nm2, float* __restrict__ partial)
{
    const int lane = threadIdx.x & 63;
    const int wave = threadIdx.x >> 6;
    const int gwave = blockIdx.x * FW + wave;
    float acc = 0.0f;
    for (int p = gwave; p < B * N; p += FBLOCKS * FW) {
        const int b = p / N, n = p - b * N;
        const float* img1 = out1 + (size_t)(b * C + lane) * WH;
        const float* img2 = out2 + (size_t)(b * C + lane) * WH;
        const int2 q1 = xy1[(size_t)b * N + n];
        const float f1 = img1[q1.x * H + q1.y];
        const int2 q2 = xy2[(size_t)b * N + n];
        const float f2 = img2[q2.x * H + q2.y];
        const float dp = f1 - f2;
        const float pos_dist = sqrtf(wave_sum64(dp * dp) + EPS);
        float neg_sum = 0.0f;
#pragma unroll
        for (int j = 0; j < M; ++j) {
            const int2 qn = nm2[(((size_t)b * M + j) * N) + n];
            const float fn = img2[qn.x * H + qn.y];
            const float dn = f1 - fn;
            neg_sum += sqrtf(wave_sum64(dn * dn) + EPS);
        }
        const float v = pos_dist - neg_sum * (1.0f / M) + MARGIN;
        acc += (v > 0.0f) ? v : 0.0f;
    }
    __shared__ float smem[FW];
    if (lane == 0) smem[wave] = acc;
    __syncthreads();
    if (threadIdx.x == 0) {
        float s = 0.0f;
#pragma unroll
        for (int i = 0; i < FW; ++i) s += smem[i];
        partial[blockIdx.x] = s;
    }
}

// ---------------------------------------------------------------------------
// Final reduce over partials
// ---------------------------------------------------------------------------
__global__ __launch_bounds__(256) void reduce_partials(
    const float* __restrict__ partial, int count, float* __restrict__ out)
{
    float s = 0.0f;
    for (int i = threadIdx.x; i < count; i += 256) s += partial[i];
    __shared__ float smem[256];
    smem[threadIdx.x] = s;
    __syncthreads();
#pragma unroll
    for (int stride = 128; stride > 0; stride >>= 1) {
        if (threadIdx.x < stride) smem[threadIdx.x] += smem[threadIdx.x + stride];
        __syncthreads();
    }
    if (threadIdx.x == 0) out[0] = smem[0] * (1.0f / (B * N));
}

extern "C" void kernel_launch(void* const* d_in, const int* in_sizes, int n_in,
                              void* d_out, int out_size, void* d_ws, size_t ws_size,
                              hipStream_t stream)
{
    const float* out1 = (const float*)d_in[0];
    const float* out2 = (const float*)d_in[1];
    const int2*  xy1  = (const int2*)d_in[2];
    const int2*  xy2  = (const int2*)d_in[3];
    const int2*  nm2  = (const int2*)d_in[4];
    float* out = (float*)d_out;

    const size_t tbytes = (size_t)B * WH * C * sizeof(float);   // 118MB
    const size_t need   = tbytes + (size_t)GBLOCKS * sizeof(float);

    if (ws_size >= need) {
        float* out2T   = (float*)d_ws;
        float* partial = (float*)((char*)d_ws + tbytes);
        transpose_out2<<<TBLOCKS, 256, 0, stream>>>(out2, out2T);
        triplet_gather<<<GBLOCKS, 256, 0, stream>>>(out1, out2T, xy1, xy2, nm2, partial);
        reduce_partials<<<1, 256, 0, stream>>>(partial, GBLOCKS, out);
    } else {
        float* partial = (float*)d_ws;                          // 8KB
        triplet_direct<<<FBLOCKS, 256, 0, stream>>>(out1, out2, xy1, xy2, nm2, partial);
        reduce_partials<<<1, 256, 0, stream>>>(partial, FBLOCKS, out);
    }
}

// Round 11
// 264.660 us; speedup vs baseline: 1.0228x; 1.0228x over previous
//
#include <hip/hip_runtime.h>
#include <math.h>

// Problem constants (from reference setup_inputs)
constexpr int B = 8, C = 64, W = 240, H = 240, N = 2000, M = 8;
constexpr int WH = W * H;               // 57600
constexpr float MARGIN = 0.5f;
constexpr float EPS = 1e-7f;

__device__ __forceinline__ float wave_sum64(float v) {
#pragma unroll
    for (int s = 32; s > 0; s >>= 1) v += __shfl_xor(v, s, 64);
    return v;  // all 64 lanes hold the full sum
}

__device__ __forceinline__ ushort f2bf(float f) {
    union { float f; uint u; } v; v.f = f;
    const uint lsb = (v.u >> 16) & 1u;
    return (ushort)((v.u + 0x7fffu + lsb) >> 16);   // RNE
}
__device__ __forceinline__ float bf2f(ushort h) {
    union { uint u; float f; } v; v.u = ((uint)h) << 16; return v.f;
}

// ---------------------------------------------------------------------------
// Kernel 1: transpose out2 (b, c, wh) fp32 -> (b, wh, c) bf16.
// 1024-thread blocks; tile = 64 ch x 576 pos.
//   reads : 2304 B contiguous per channel (64 streams/block)
//   writes: 576 pos x 128 B = 73728 B fully contiguous per block
// LDS: 64 rows x 578 ushorts (73984 B) -> row stride 289 words == 1 mod 32,
// so column reads across c are <=2-way bank aliasing (free).
// ---------------------------------------------------------------------------
constexpr int TP2 = 576;                 // positions per tile
constexpr int NTILE = WH / TP2;          // 100
constexpr int ROWU = TP2 + 2;            // 578 ushorts per LDS row
constexpr int T2BLOCKS = B * NTILE;      // 800

__global__ __launch_bounds__(1024) void transpose_bf16(
    const float* __restrict__ src, ushort* __restrict__ dst)
{
    __shared__ ushort tile[C * ROWU];
    const int b   = blockIdx.x / NTILE;
    const int p0  = (blockIdx.x % NTILE) * TP2;
    const int tid = threadIdx.x;

    // READ phase: channel c = tid>>4; 16 threads per channel, 9 float4 each.
    {
        const int c   = tid >> 4;
        const int t16 = tid & 15;
        const float4* s4 = (const float4*)(src + (size_t)(b * C + c) * WH + p0);
        uint* trow = (uint*)(tile + c * ROWU);    // 1156B row stride, 4B aligned
#pragma unroll
        for (int i = 0; i < 9; ++i) {
            const int p4 = t16 + i * 16;          // float4 index 0..143
            const float4 v = s4[p4];
            const uint u0 = (uint)f2bf(v.x) | ((uint)f2bf(v.y) << 16);
            const uint u1 = (uint)f2bf(v.z) | ((uint)f2bf(v.w) << 16);
            trow[p4 * 2 + 0] = u0;
            trow[p4 * 2 + 1] = u1;
        }
    }
    __syncthreads();

    // WRITE phase: output uint2 o covers (position p, channel-quad cg).
    // Block writes 73728 B contiguous starting at (b*WH + p0)*64 ushorts.
    {
        uint2* d2 = (uint2*)dst;                  // uint2 = 4 bf16
#pragma unroll
        for (int i = 0; i < 9; ++i) {
            const int o  = i * 1024 + tid;        // 0..9215
            const int p  = o >> 4;                // 0..575
            const int cg = o & 15;                // channel quad
            const int c0 = cg * 4;
            const ushort x0 = tile[(c0 + 0) * ROWU + p];
            const ushort x1 = tile[(c0 + 1) * ROWU + p];
            const ushort x2 = tile[(c0 + 2) * ROWU + p];
            const ushort x3 = tile[(c0 + 3) * ROWU + p];
            uint2 ov;
            ov.x = (uint)x0 | ((uint)x1 << 16);
            ov.y = (uint)x2 | ((uint)x3 << 16);
            d2[((size_t)b * WH + p0 + p) * 16 + cg] = ov;
        }
    }
}

// ---------------------------------------------------------------------------
// Kernel 2: gather + triplet math.  1 point per wave, 16000 waves.
// out2T is bf16 (b, wh, c): one 128B contiguous vector per gather.
// ---------------------------------------------------------------------------
constexpr int GW = 4;                          // waves per block
constexpr int GBLOCKS = (B * N) / GW;          // 4000

__global__ __launch_bounds__(256) void triplet_gather(
    const float* __restrict__ out1, const ushort* __restrict__ out2T,
    const int2* __restrict__ xy1, const int2* __restrict__ xy2,
    const int2* __restrict__ nm2, float* __restrict__ partial)
{
    const int lane = threadIdx.x & 63;         // = channel
    const int wave = threadIdx.x >> 6;
    const int p = blockIdx.x * GW + wave;      // 0..15999
    const int b = p / N, n = p - b * N;

    // f1: direct strided gather from out1 (not transposed, fp32)
    const int2 q1 = xy1[(size_t)b * N + n];
    const float f1 = out1[(size_t)(b * C + lane) * WH + q1.x * H + q1.y];

    const ushort* base2 = out2T + (size_t)b * WH * C;

    // f2: contiguous 128B bf16 vector
    const int2 q2 = xy2[(size_t)b * N + n];
    const float f2 = bf2f(base2[(size_t)(q2.x * H + q2.y) * C + lane]);
    const float dp = f1 - f2;
    const float pos_dist = sqrtf(wave_sum64(dp * dp) + EPS);

    float neg_sum = 0.0f;
#pragma unroll
    for (int j = 0; j < M; ++j) {
        const int2 qn = nm2[(((size_t)b * M + j) * N) + n];
        const float fn = bf2f(base2[(size_t)(qn.x * H + qn.y) * C + lane]);
        const float dn = f1 - fn;
        neg_sum += sqrtf(wave_sum64(dn * dn) + EPS);
    }

    const float v = pos_dist - neg_sum * (1.0f / M) + MARGIN;
    const float res = (v > 0.0f) ? v : 0.0f;

    __shared__ float sm[GW];
    if (lane == 0) sm[wave] = res;
    __syncthreads();
    if (threadIdx.x == 0) {
        float s = 0.0f;
#pragma unroll
        for (int i = 0; i < GW; ++i) s += sm[i];
        partial[blockIdx.x] = s;
    }
}

// ---------------------------------------------------------------------------
// Fallback direct kernel (used only if ws too small for the transpose buffer)
// ---------------------------------------------------------------------------
constexpr int FBLOCKS = 2000, FW = 4;

__global__ __launch_bounds__(256) void triplet_direct(
    const float* __restrict__ out1, const float* __restrict__ out2,
    const int2* __restrict__ xy1, const int2* __restrict__ xy2,
    const int2* __restrict__ nm2, float* __restrict__ partial)
{
    const int lane = threadIdx.x & 63;
    const int wave = threadIdx.x >> 6;
    const int gwave = blockIdx.x * FW + wave;
    float acc = 0.0f;
    for (int p = gwave; p < B * N; p += FBLOCKS * FW) {
        const int b = p / N, n = p - b * N;
        const float* img1 = out1 + (size_t)(b * C + lane) * WH;
        const float* img2 = out2 + (size_t)(b * C + lane) * WH;
        const int2 q1 = xy1[(size_t)b * N + n];
        const float f1 = img1[q1.x * H + q1.y];
        const int2 q2 = xy2[(size_t)b * N + n];
        const float f2 = img2[q2.x * H + q2.y];
        const float dp = f1 - f2;
        const float pos_dist = sqrtf(wave_sum64(dp * dp) + EPS);
        float neg_sum = 0.0f;
#pragma unroll
        for (int j = 0; j < M; ++j) {
            const int2 qn = nm2[(((size_t)b * M + j) * N) + n];
            const float fn = img2[qn.x * H + qn.y];
            const float dn = f1 - fn;
            neg_sum += sqrtf(wave_sum64(dn * dn) + EPS);
        }
        const float v = pos_dist - neg_sum * (1.0f / M) + MARGIN;
        acc += (v > 0.0f) ? v : 0.0f;
    }
    __shared__ float smem[FW];
    if (lane == 0) smem[wave] = acc;
    __syncthreads();
    if (threadIdx.x == 0) {
        float s = 0.0f;
#pragma unroll
        for (int i = 0; i < FW; ++i) s += smem[i];
        partial[blockIdx.x] = s;
    }
}

// ---------------------------------------------------------------------------
// Final reduce over partials
// ---------------------------------------------------------------------------
__global__ __launch_bounds__(256) void reduce_partials(
    const float* __restrict__ partial, int count, float* __restrict__ out)
{
    float s = 0.0f;
    for (int i = threadIdx.x; i < count; i += 256) s += partial[i];
    __shared__ float smem[256];
    smem[threadIdx.x] = s;
    __syncthreads();
#pragma unroll
    for (int stride = 128; stride > 0; stride >>= 1) {
        if (threadIdx.x < stride) smem[threadIdx.x] += smem[threadIdx.x + stride];
        __syncthreads();
    }
    if (threadIdx.x == 0) out[0] = smem[0] * (1.0f / (B * N));
}

extern "C" void kernel_launch(void* const* d_in, const int* in_sizes, int n_in,
                              void* d_out, int out_size, void* d_ws, size_t ws_size,
                              hipStream_t stream)
{
    const float* out1 = (const float*)d_in[0];
    const float* out2 = (const float*)d_in[1];
    const int2*  xy1  = (const int2*)d_in[2];
    const int2*  xy2  = (const int2*)d_in[3];
    const int2*  nm2  = (const int2*)d_in[4];
    float* out = (float*)d_out;

    const size_t tbytes = (size_t)B * WH * C * sizeof(ushort);  // 59MB bf16
    const size_t need   = tbytes + (size_t)GBLOCKS * sizeof(float);

    if (ws_size >= need) {
        ushort* out2T  = (ushort*)d_ws;
        float* partial = (float*)((char*)d_ws + tbytes);
        transpose_bf16<<<T2BLOCKS, 1024, 0, stream>>>(out2, out2T);
        triplet_gather<<<GBLOCKS, 256, 0, stream>>>(out1, out2T, xy1, xy2, nm2, partial);
        reduce_partials<<<1, 256, 0, stream>>>(partial, GBLOCKS, out);
    } else {
        float* partial = (float*)d_ws;                          // 8KB
        triplet_direct<<<FBLOCKS, 256, 0, stream>>>(out1, out2, xy1, xy2, nm2, partial);
        reduce_partials<<<1, 256, 0, stream>>>(partial, FBLOCKS, out);
    }
}